// Round 3
// baseline (2720.148 us; speedup 1.0000x reference)
//
#include <hip/hip_runtime.h>
#include <hip/hip_bf16.h>

// Bi-LSTM persistent kernel v3. B=32, T=512, D=H=512.
// 4 sync groups = dir(2) x batch-half(2); 32 WGs/group, 16 rows/group, 16 h-cols/WG.
// Sync: NO barrier/counter. h published as tagged 8B pairs {tag=s+1, 2xbf16};
// consumers data-poll the pairs they need with agent-scope atomic loads.
#define Bz 32
#define Tz 512
#define Dz 512
#define Hz 512
#define NG 4      // sync groups
#define GWG 32    // workgroups per group
#define ROWS 16   // batch rows per group (one MFMA m-tile)
#define COLS 16   // h-cols per WG

typedef __attribute__((ext_vector_type(8))) short short8;
typedef __attribute__((ext_vector_type(4))) short short4v;
typedef __attribute__((ext_vector_type(4))) float f32x4;

// tagged-pair buffers: [group][parity][row][pair], 8B each = {u32 tag, u32 2xbf16}
#define PAIRS (Hz / 2)                       // 256 pairs per row
#define TPU   (ROWS * PAIRS)                 // u64 count per (group,parity) = 4096
#define TPB   (TPU * 8)                      // 32 KB
#define WS_TP 0
#define WS_X  (NG * 2 * TPB)                 // 256 KB, then x in bf16 (16 MB)
#define WS_NEED ((size_t)WS_X + (size_t)Bz * Tz * Dz * 2)

__device__ __forceinline__ unsigned short f2bf(float f) {
    return __builtin_bit_cast(unsigned short, __float2bfloat16(f));
}
__device__ __forceinline__ float rcp_(float x) { return __builtin_amdgcn_rcpf(x); }
__device__ __forceinline__ float fsig(float x) { return rcp_(1.0f + __expf(-x)); }
__device__ __forceinline__ float ftanh(float x) {
    float t = __expf(-2.0f * fabsf(x));
    return copysignf((1.0f - t) * rcp_(1.0f + t), x);
}
__device__ __forceinline__ short8 mk8(unsigned long long lo, unsigned long long hi) {
    short4v a = __builtin_bit_cast(short4v, lo);
    short4v b = __builtin_bit_cast(short4v, hi);
    short8 r;
    r[0]=a[0]; r[1]=a[1]; r[2]=a[2]; r[3]=a[3];
    r[4]=b[0]; r[5]=b[1]; r[6]=b[2]; r[7]=b[3];
    return r;
}

// Zero tagged-pair region (tag 0 + h=0 is the s=0 initial state); x fp32->bf16.
__global__ void init_kernel(const float* __restrict__ x, unsigned char* __restrict__ ws, int do_x) {
    int tid = blockIdx.x * blockDim.x + threadIdx.x;
    unsigned int* w32 = (unsigned int*)ws;
    if (tid < (WS_X / 4)) w32[tid] = 0u;
    if (do_x) {
        const int n4 = (Bz * Tz * Dz) / 4;
        if (tid < n4) {
            const float4* xin = (const float4*)x;
            float4 v = xin[tid];
            unsigned int u0 = (unsigned)f2bf(v.x) | ((unsigned)f2bf(v.y) << 16);
            unsigned int u1 = (unsigned)f2bf(v.z) | ((unsigned)f2bf(v.w) << 16);
            unsigned int* xo = (unsigned int*)(ws + WS_X);
            xo[tid * 2]     = u0;
            xo[tid * 2 + 1] = u1;
        }
    }
}

template <bool XB>
__launch_bounds__(256, 1)
__global__ void lstm_kernel(const float* __restrict__ xf,
                            const float* __restrict__ Wf, const float* __restrict__ bf,
                            const float* __restrict__ Wb, const float* __restrict__ bb,
                            float* __restrict__ out, unsigned char* __restrict__ ws) {
    const int bi   = blockIdx.x;
    const int dir  = bi & 1;
    const int grp  = (bi >> 1) & 1;
    const int wg   = bi >> 2;            // 0..31
    const int gid  = dir * 2 + grp;
    const int j0   = wg * COLS;
    const int b0   = grp * ROWS;
    const int tid  = threadIdx.x;
    const int wave = tid >> 6;
    const int lane = tid & 63;
    const int nidx = lane & 15;          // B-frag col n / A-frag row m
    const int quad = lane >> 4;

    const float* W    = dir ? Wb : Wf;
    const float* bias = dir ? bb : bf;

    unsigned long long* tp = (unsigned long long*)(ws + WS_TP + gid * 2 * TPB);
    const unsigned short* xbf = (const unsigned short*)(ws + WS_X);

    __shared__ float part[4][4][16][17];  // wave, gate, row, col (+1 pad)

    // --- one-time: W slice as B-fragments in registers (bf16) ---
    // wave 0/1: K rows [0,256)/[256,512) of Wx; wave 2/3: rows [0,256)/[256,512) of Wh.
    short8 bfrag[8][4];
    {
        const int krow0 = (wave < 2) ? wave * 256 : 512 + (wave - 2) * 256;
        #pragma unroll
        for (int i = 0; i < 8; ++i) {
            #pragma unroll
            for (int g = 0; g < 4; ++g) {
                short8 v;
                #pragma unroll
                for (int jj = 0; jj < 8; ++jj) {
                    int krow = krow0 + i * 32 + quad * 8 + jj;
                    v[jj] = (short)f2bf(W[krow * (4 * Hz) + g * 512 + j0 + nidx]);
                }
                bfrag[i][g] = v;
            }
        }
    }

    // --- per-thread epilogue state: one (row,col) each ---
    const int erow = tid >> 4;
    const int ecol = tid & 15;
    float bia[4];
    #pragma unroll
    for (int g = 0; g < 4; ++g) bia[g] = bias[g * 512 + j0 + ecol];
    float creg = 0.f;
    const size_t outbase = ((size_t)(b0 + erow) * Tz) * (2 * Hz) + dir * Hz + j0 + ecol;

    for (int s = 0; s < Tz; ++s) {
        const int t = dir ? (Tz - 1 - s) : s;
        f32x4 acc[4] = {{0,0,0,0},{0,0,0,0},{0,0,0,0},{0,0,0,0}};

        if (wave < 2) {
            // x part — independent of h, overlaps consumers' polling.
            const int kb = wave * 256;
            short8 a[8];
            if (XB) {
                #pragma unroll
                for (int i = 0; i < 8; ++i) {
                    int k = kb + i * 32 + quad * 8;
                    a[i] = *(const short8*)(xbf + (((b0 + nidx) * Tz + t) * Dz + k));
                }
            } else {
                #pragma unroll
                for (int i = 0; i < 8; ++i) {
                    int k = kb + i * 32 + quad * 8;
                    const float* q = xf + (((b0 + nidx) * Tz + t) * Dz + k);
                    short8 sv;
                    #pragma unroll
                    for (int jj = 0; jj < 8; ++jj) sv[jj] = (short)f2bf(q[jj]);
                    a[i] = sv;
                }
            }
            #pragma unroll
            for (int i = 0; i < 8; ++i)
                #pragma unroll
                for (int g = 0; g < 4; ++g)
                    acc[g] = __builtin_amdgcn_mfma_f32_16x16x32_bf16(a[i], bfrag[i][g], acc[g], 0, 0, 0);
        } else {
            // h part: data-poll the tagged pairs this lane needs for step s.
            unsigned long long* tpr = tp + (s & 1) * TPU;
            const unsigned tg = (unsigned)s;
            const int pb0 = ((wave - 2) * 256) >> 1;   // pair base for this wave's K-slice
            unsigned long long v[8][4];
            for (;;) {
                #pragma unroll
                for (int i = 0; i < 8; ++i) {
                    int p = nidx * PAIRS + pb0 + i * 16 + quad * 4;
                    #pragma unroll
                    for (int jq = 0; jq < 4; ++jq)
                        v[i][jq] = __hip_atomic_load(tpr + p + jq,
                                                     __ATOMIC_RELAXED, __HIP_MEMORY_SCOPE_AGENT);
                }
                int ok = 1;
                #pragma unroll
                for (int i = 0; i < 8; ++i)
                    #pragma unroll
                    for (int jq = 0; jq < 4; ++jq)
                        ok &= ((unsigned)v[i][jq] == tg);
                if (__ballot(ok) == ~0ull) break;
                __builtin_amdgcn_s_sleep(1);
            }
            #pragma unroll
            for (int i = 0; i < 8; ++i) {
                unsigned long long lo = (v[i][0] >> 32) | ((v[i][1] >> 32) << 32);
                unsigned long long hi = (v[i][2] >> 32) | ((v[i][3] >> 32) << 32);
                short8 a = mk8(lo, hi);
                #pragma unroll
                for (int g = 0; g < 4; ++g)
                    acc[g] = __builtin_amdgcn_mfma_f32_16x16x32_bf16(a, bfrag[i][g], acc[g], 0, 0, 0);
            }
        }

        // C/D layout: col = lane&15, row = quad*4 + reg
        {
            const int r0 = quad * 4;
            #pragma unroll
            for (int g = 0; g < 4; ++g)
                #pragma unroll
                for (int r = 0; r < 4; ++r)
                    part[wave][g][r0 + r][nidx] = acc[g][r];
        }
        __syncthreads();

        // epilogue: one (row,col) per thread
        {
            float z[4];
            #pragma unroll
            for (int g = 0; g < 4; ++g)
                z[g] = bia[g] + part[0][g][erow][ecol] + part[1][g][erow][ecol]
                             + part[2][g][erow][ecol] + part[3][g][erow][ecol];
            float c = fsig(z[1]) * creg + fsig(z[0]) * ftanh(z[3]);
            creg = c;
            float hv = fsig(z[2]) * ftanh(c);

            // publish: even-col lanes store {tag=s+1, pack(h_even, h_odd)} as one 8B word
            float hp = __shfl_xor(hv, 1);
            if ((ecol & 1) == 0) {
                unsigned d = (unsigned)f2bf(hv) | ((unsigned)f2bf(hp) << 16);
                unsigned long long val = ((unsigned long long)d << 32) | (unsigned)(s + 1);
                unsigned long long* tpw = tp + ((s + 1) & 1) * TPU;
                int p = erow * PAIRS + ((j0 + ecol) >> 1);
                __hip_atomic_store(tpw + p, val, __ATOMIC_RELAXED, __HIP_MEMORY_SCOPE_AGENT);
            }
            out[outbase + (size_t)t * (2 * Hz)] = hv;
        }
        __syncthreads();   // guard LDS reuse for next step
    }
}

extern "C" void kernel_launch(void* const* d_in, const int* in_sizes, int n_in,
                              void* d_out, int out_size, void* d_ws, size_t ws_size,
                              hipStream_t stream) {
    const float* x  = (const float*)d_in[0];
    const float* Wf = (const float*)d_in[1];
    const float* bf = (const float*)d_in[2];
    const float* Wb = (const float*)d_in[3];
    const float* bb = (const float*)d_in[4];
    float* out = (float*)d_out;
    unsigned char* ws = (unsigned char*)d_ws;
    const bool xb = (ws_size >= WS_NEED);

    init_kernel<<<8192, 256, 0, stream>>>(x, ws, xb ? 1 : 0);
    if (xb)
        lstm_kernel<true><<<NG * GWG, 256, 0, stream>>>(x, Wf, bf, Wb, bb, out, ws);
    else
        lstm_kernel<false><<<NG * GWG, 256, 0, stream>>>(x, Wf, bf, Wb, bb, out, ws);
}

// Round 4
// 1946.104 us; speedup vs baseline: 1.3977x; 1.3977x over previous
//
#include <hip/hip_runtime.h>
#include <hip/hip_bf16.h>

// Bi-LSTM persistent kernel v4. B=32, T=512, D=H=512.
// 4 sync groups = dir(2) x batch-half(2); 32 WGs/group, 16 rows/group, 16 h-cols/WG.
// Sync: per-WG flag array (32 flags @ 16B stride, plain relaxed agent stores);
// consumers poll all 32 flags with ONE vector load + ballot. No RMW anywhere.
#define Bz 32
#define Tz 512
#define Dz 512
#define Hz 512
#define NG 4      // sync groups
#define GWG 32    // workgroups per group
#define ROWS 16   // batch rows per group (one MFMA m-tile)
#define COLS 16   // h-cols per WG

typedef __attribute__((ext_vector_type(8))) short short8;
typedef __attribute__((ext_vector_type(4))) short short4v;
typedef __attribute__((ext_vector_type(4))) float f32x4;

#define HBUF (ROWS * Hz * 2)                 // 16 KB per (group,parity)
#define FLGB 512                             // 32 flags @ 16B stride per group
#define WS_FLG 0                             // NG * 512 B
#define WS_H   (NG * FLGB)
#define WS_X   (WS_H + NG * 2 * HBUF)        // x in bf16: 16 MB
#define WS_NEED ((size_t)WS_X + (size_t)Bz * Tz * Dz * 2)

__device__ __forceinline__ unsigned short f2bf(float f) {
    return __builtin_bit_cast(unsigned short, __float2bfloat16(f));
}
__device__ __forceinline__ float rcp_(float x) { return __builtin_amdgcn_rcpf(x); }
__device__ __forceinline__ float fsig(float x) { return rcp_(1.0f + __expf(-x)); }
__device__ __forceinline__ float ftanh(float x) {
    float t = __expf(-2.0f * fabsf(x));
    return copysignf((1.0f - t) * rcp_(1.0f + t), x);
}
__device__ __forceinline__ short8 mk8(unsigned long long lo, unsigned long long hi) {
    short4v a = __builtin_bit_cast(short4v, lo);
    short4v b = __builtin_bit_cast(short4v, hi);
    short8 r;
    r[0]=a[0]; r[1]=a[1]; r[2]=a[2]; r[3]=a[3];
    r[4]=b[0]; r[5]=b[1]; r[6]=b[2]; r[7]=b[3];
    return r;
}

__global__ void init_kernel(const float* __restrict__ x, unsigned char* __restrict__ ws, int do_x) {
    int tid = blockIdx.x * blockDim.x + threadIdx.x;
    unsigned int* w32 = (unsigned int*)ws;
    if (tid < (WS_X / 4)) w32[tid] = 0u;   // flags + all h buffers
    if (do_x) {
        const int n4 = (Bz * Tz * Dz) / 4;
        if (tid < n4) {
            const float4* xin = (const float4*)x;
            float4 v = xin[tid];
            unsigned int u0 = (unsigned)f2bf(v.x) | ((unsigned)f2bf(v.y) << 16);
            unsigned int u1 = (unsigned)f2bf(v.z) | ((unsigned)f2bf(v.w) << 16);
            unsigned int* xo = (unsigned int*)(ws + WS_X);
            xo[tid * 2]     = u0;
            xo[tid * 2 + 1] = u1;
        }
    }
}

template <bool XB>
__launch_bounds__(256, 1)
__global__ void lstm_kernel(const float* __restrict__ xf,
                            const float* __restrict__ Wf, const float* __restrict__ bf,
                            const float* __restrict__ Wb, const float* __restrict__ bb,
                            float* __restrict__ out, unsigned char* __restrict__ ws) {
    const int bi   = blockIdx.x;
    const int dir  = bi & 1;
    const int grp  = (bi >> 1) & 1;
    const int wg   = bi >> 2;            // 0..31
    const int gid  = dir * 2 + grp;
    const int j0   = wg * COLS;
    const int b0   = grp * ROWS;
    const int tid  = threadIdx.x;
    const int wave = tid >> 6;
    const int lane = tid & 63;
    const int nidx = lane & 15;          // B-frag col n / A-frag row m
    const int quad = lane >> 4;

    const float* W    = dir ? Wb : Wf;
    const float* bias = dir ? bb : bf;

    unsigned int* flg = (unsigned int*)(ws + WS_FLG + gid * FLGB);  // flag[w] at w*4 u32s (16B stride)
    unsigned char* hbase = ws + WS_H + gid * 2 * HBUF;              // + parity*HBUF
    const unsigned short* xbf = (const unsigned short*)(ws + WS_X);

    __shared__ float part[4][4][16][17];  // wave, gate, row, col (+1 pad)

    // --- one-time: W slice as B-fragments in registers (bf16) ---
    // wave 0/1: K rows [0,256)/[256,512) of Wx; wave 2/3: rows [0,256)/[256,512) of Wh.
    short8 bfrag[8][4];
    {
        const int krow0 = (wave < 2) ? wave * 256 : 512 + (wave - 2) * 256;
        #pragma unroll
        for (int i = 0; i < 8; ++i) {
            #pragma unroll
            for (int g = 0; g < 4; ++g) {
                short8 v;
                #pragma unroll
                for (int jj = 0; jj < 8; ++jj) {
                    int krow = krow0 + i * 32 + quad * 8 + jj;
                    v[jj] = (short)f2bf(W[krow * (4 * Hz) + g * 512 + j0 + nidx]);
                }
                bfrag[i][g] = v;
            }
        }
    }

    // --- per-thread epilogue state: one (row,col) each ---
    const int erow = tid >> 4;
    const int ecol = tid & 15;
    float bia[4];
    #pragma unroll
    for (int g = 0; g < 4; ++g) bia[g] = bias[g * 512 + j0 + ecol];
    float creg = 0.f;
    const size_t outbase = ((size_t)(b0 + erow) * Tz) * (2 * Hz) + dir * Hz + j0 + ecol;

    int par = 0;
    for (int s = 0; s < Tz; ++s) {
        const int t = dir ? (Tz - 1 - s) : s;
        f32x4 acc[4] = {{0,0,0,0},{0,0,0,0},{0,0,0,0},{0,0,0,0}};

        if (wave < 2) {
            // x part — independent of h, overlaps consumers' polling.
            const int kb = wave * 256;
            short8 a[8];
            if (XB) {
                #pragma unroll
                for (int i = 0; i < 8; ++i) {
                    int k = kb + i * 32 + quad * 8;
                    a[i] = *(const short8*)(xbf + (((b0 + nidx) * Tz + t) * Dz + k));
                }
            } else {
                #pragma unroll
                for (int i = 0; i < 8; ++i) {
                    int k = kb + i * 32 + quad * 8;
                    const float* q = xf + (((b0 + nidx) * Tz + t) * Dz + k);
                    short8 sv;
                    #pragma unroll
                    for (int jj = 0; jj < 8; ++jj) sv[jj] = (short)f2bf(q[jj]);
                    a[i] = sv;
                }
            }
            #pragma unroll
            for (int i = 0; i < 8; ++i)
                #pragma unroll
                for (int g = 0; g < 4; ++g)
                    acc[g] = __builtin_amdgcn_mfma_f32_16x16x32_bf16(a[i], bfrag[i][g], acc[g], 0, 0, 0);
        } else {
            // h part: one-instruction poll of all 32 per-WG flags (8 lines), then load h once.
            {
                const unsigned tgt = (unsigned)s;
                const int fi = (lane & 31) * 4;   // 16B stride
                for (;;) {
                    unsigned f = __hip_atomic_load(flg + fi, __ATOMIC_RELAXED, __HIP_MEMORY_SCOPE_AGENT);
                    if (__ballot(f >= tgt) == ~0ull) break;
                    __builtin_amdgcn_s_sleep(1);
                }
            }
            const unsigned long long* hb = (const unsigned long long*)(hbase + par * HBUF);
            const int kb = (wave - 2) * 256;
            short8 a[8];
            #pragma unroll
            for (int i = 0; i < 8; ++i) {
                int k  = kb + i * 32 + quad * 8;
                int i0 = (nidx * Hz + k) >> 2;   // u64 index (4 bf16 each)
                unsigned long long l0 = __hip_atomic_load(hb + i0,     __ATOMIC_RELAXED, __HIP_MEMORY_SCOPE_AGENT);
                unsigned long long l1 = __hip_atomic_load(hb + i0 + 1, __ATOMIC_RELAXED, __HIP_MEMORY_SCOPE_AGENT);
                a[i] = mk8(l0, l1);
            }
            #pragma unroll
            for (int i = 0; i < 8; ++i)
                #pragma unroll
                for (int g = 0; g < 4; ++g)
                    acc[g] = __builtin_amdgcn_mfma_f32_16x16x32_bf16(a[i], bfrag[i][g], acc[g], 0, 0, 0);
        }

        // C/D layout: col = lane&15, row = quad*4 + reg
        {
            const int r0 = quad * 4;
            #pragma unroll
            for (int g = 0; g < 4; ++g)
                #pragma unroll
                for (int r = 0; r < 4; ++r)
                    part[wave][g][r0 + r][nidx] = acc[g][r];
        }
        __syncthreads();

        // epilogue: one (row,col) per thread
        float hv;
        {
            float z[4];
            #pragma unroll
            for (int g = 0; g < 4; ++g)
                z[g] = bia[g] + part[0][g][erow][ecol] + part[1][g][erow][ecol]
                             + part[2][g][erow][ecol] + part[3][g][erow][ecol];
            float c = fsig(z[1]) * creg + fsig(z[0]) * ftanh(z[3]);
            creg = c;
            hv = fsig(z[2]) * ftanh(c);
            // pack 2 cols into one u32 store (even-col lanes)
            float hp = __shfl_xor(hv, 1);
            if ((ecol & 1) == 0) {
                unsigned d = (unsigned)f2bf(hv) | ((unsigned)f2bf(hp) << 16);
                unsigned* hw = (unsigned*)(hbase + (par ^ 1) * HBUF);
                __hip_atomic_store(hw + erow * (Hz / 2) + ((j0 + ecol) >> 1), d,
                                   __ATOMIC_RELAXED, __HIP_MEMORY_SCOPE_AGENT);
            }
        }

        // Drain ONLY the h stores (out store not yet issued), then publish flag.
        asm volatile("s_waitcnt vmcnt(0)" ::: "memory");
        __syncthreads();
        if (tid == 0)
            __hip_atomic_store(flg + wg * 4, (unsigned)(s + 1),
                               __ATOMIC_RELAXED, __HIP_MEMORY_SCOPE_AGENT);
        // out store AFTER the flag: its HBM ack overlaps the next step.
        out[outbase + (size_t)t * (2 * Hz)] = hv;
        par ^= 1;
    }
}

extern "C" void kernel_launch(void* const* d_in, const int* in_sizes, int n_in,
                              void* d_out, int out_size, void* d_ws, size_t ws_size,
                              hipStream_t stream) {
    const float* x  = (const float*)d_in[0];
    const float* Wf = (const float*)d_in[1];
    const float* bf = (const float*)d_in[2];
    const float* Wb = (const float*)d_in[3];
    const float* bb = (const float*)d_in[4];
    float* out = (float*)d_out;
    unsigned char* ws = (unsigned char*)d_ws;
    const bool xb = (ws_size >= WS_NEED);

    init_kernel<<<8192, 256, 0, stream>>>(x, ws, xb ? 1 : 0);
    if (xb)
        lstm_kernel<true><<<NG * GWG, 256, 0, stream>>>(x, Wf, bf, Wb, bb, out, ws);
    else
        lstm_kernel<false><<<NG * GWG, 256, 0, stream>>>(x, Wf, bf, Wb, bb, out, ws);
}